// Round 1
// baseline (204.673 us; speedup 1.0000x reference)
//
#include <hip/hip_runtime.h>
#include <math.h>

typedef unsigned short u16;
typedef unsigned int   u32;
typedef __attribute__((ext_vector_type(8))) short bf16x8;
typedef __attribute__((ext_vector_type(4))) float floatx4;
typedef __attribute__((ext_vector_type(4))) _Float16 halfx4;
typedef __attribute__((ext_vector_type(2))) unsigned int uintx2;

// B=2, S=2048, D=1024, H=16, Dh=64, M=B*S=4096
#define SEQ 2048
#define DM  1024
#define NH  16
#define DH  64
#define MM  4096
#define QSCALE 0.18033688011112042f   // 0.125 * log2(e), folded into Q

__device__ __forceinline__ u16 f2bf(float f) {
    u32 u = __builtin_bit_cast(u32, f);
    u += 0x7fffu + ((u >> 16) & 1u);
    return (u16)(u >> 16);
}

__device__ __forceinline__ void async16(const void* g, void* l) {
    __builtin_amdgcn_global_load_lds(
        (const __attribute__((address_space(1))) void*)g,
        (__attribute__((address_space(3))) void*)l, 16, 0, 0);
}

// ---------------- prep: fp32 -> bf16 shuffled layout + RoPE table -------------------
// Shuffled layout: tile (rowblk=row/16, ktile=col/32); element [m=lm][k=quad*8+j]
// stored flat at (rowblk*32 + ktile)*512 + lane*8 + j. One dwordx4/lane per fragment.
// First 256 linear blocks additionally fill the RoPE table (2048x32 float2).
__global__ __launch_bounds__(256) void prep_kernel(const float* __restrict__ x,
                                                   const float* __restrict__ w0,
                                                   const float* __restrict__ w1,
                                                   const float* __restrict__ w2,
                                                   const float* __restrict__ w3,
                                                   u16* __restrict__ Xsh,
                                                   u16* __restrict__ Wsh,
                                                   const int* __restrict__ pos,
                                                   float2* __restrict__ tab) {
    const int bid = blockIdx.x, cb = blockIdx.y, tid = threadIdx.x;

    // RoPE table side-job
    int lin = bid * 16 + cb;
    if (lin < 256) {
        int i = lin * 256 + tid;       // 65536 = 2048*32
        int p = i >> 5, d2 = i & 31;
        float freq = __expf(-(float)d2 * (9.2103403719761836f / 32.0f));
        float sv, cv;
        sincosf((float)pos[p] * freq, &sv, &cv);
        tab[i] = make_float2(cv, sv);
    }

    const float* src; u16* dst; int row0;
    if (bid < 64) { src = x; dst = Xsh; row0 = bid * 64; }
    else {
        int wi = (bid - 64) >> 4;
        src = (wi == 0) ? w0 : (wi == 1) ? w1 : (wi == 2) ? w2 : w3;
        dst = Wsh + (size_t)wi * DM * DM;
        row0 = ((bid - 64) & 15) * 64;
    }
    __shared__ __align__(16) u16 t[64 * 64];   // 8-elem chunks XOR-swizzled by row&7
#pragma unroll
    for (int rep = 0; rep < 4; ++rep) {
        int f = rep * 256 + tid;
        int r = f >> 4, c4 = f & 15;
        float4 v = *(const float4*)&src[(size_t)(row0 + r) * DM + cb * 64 + c4 * 4];
        uint2 pk;
        pk.x = (u32)f2bf(v.x) | ((u32)f2bf(v.y) << 16);
        pk.y = (u32)f2bf(v.z) | ((u32)f2bf(v.w) << 16);
        int ch = (c4 >> 1) ^ (r & 7);
        *(uint2*)&t[r * 64 + ch * 8 + (c4 & 1) * 4] = pk;
    }
    __syncthreads();
#pragma unroll
    for (int rep = 0; rep < 2; ++rep) {
        int s = rep * 256 + tid;
        int tile = s >> 6, l = s & 63;
        int mt = tile >> 1, kt = tile & 1, lm = l & 15, quad = l >> 4;
        int m = mt * 16 + lm;
        uint4 v = *(const uint4*)&t[m * 64 + ((kt * 4 + quad) ^ (m & 7)) * 8];
        size_t rowblk = (size_t)(row0 >> 4) + mt;
        size_t ktile  = cb * 2 + kt;
        *(uint4*)&dst[(rowblk * 32 + ktile) * 512 + l * 8] = v;
    }
}

// ---------------- NT GEMM, LDS-staged (m97 structure): C[M,1024] = A * W^T ----------
// 128 x 128 block tile, 4 waves (2x2), 64x64 per wave. BK=64 (2 ktiles).
// Single-buffer 32KB LDS staged via global_load_lds dwordx4; 2 barriers per K-step.
// Operands are in the shuffled chunk layout, so staging is layout-preserving:
// each (rowblk,ktile) chunk is 1KB, lane order = base + lane*16B (linear dest OK),
// and fragment ds_read_b128 at lane*16B is bank-conflict-free.
// z==2 (V) writes V^T f16; RoPE fused on Q,K; softmax scale folded into Q.
template<bool OUTF32>
__global__ __launch_bounds__(256) void gemm_ls(const u16* __restrict__ Ash,
                                               const u16* __restrict__ Wbase,
                                               u16* __restrict__ outbf,
                                               float* __restrict__ outf,
                                               _Float16* __restrict__ vtout,
                                               const float2* __restrict__ ropetab,
                                               int ropeMask) {
    const int z  = blockIdx.z;
    const u16* Wp = Wbase + (size_t)z * (DM * DM);
    const int m0 = blockIdx.x * 128, n0 = blockIdx.y * 128;
    const int tid  = threadIdx.x;
    const int lane = tid & 63, w = tid >> 6;
    const int wr = w >> 1, wc = w & 1;
    const int lm = lane & 15, quad = lane >> 4;

    __shared__ __align__(16) u16 lsA[16 * 512];   // 8 rowblks x 2 ktiles x 1KB = 16KB
    __shared__ __align__(16) u16 lsB[16 * 512];

    // global chunk bases (lane offset folded in; chunks stride 512 elems)
    const u16* aG = Ash + ((size_t)(m0 >> 4) * 32) * 512 + lane * 8;
    const u16* bG = Wp  + ((size_t)(n0 >> 4) * 32) * 512 + lane * 8;

    floatx4 acc[4][4];
    const floatx4 z4 = {0.f, 0.f, 0.f, 0.f};
#pragma unroll
    for (int mt = 0; mt < 4; ++mt)
#pragma unroll
        for (int nt = 0; nt < 4; ++nt) acc[mt][nt] = z4;

    for (int it = 0; it < 16; ++it) {
        // stage K-step it: 32 chunks (16 A + 16 B); wave w stages chunks w*4..w*4+3 of each
#pragma unroll
        for (int rep = 0; rep < 4; ++rep) {
            int c = w * 4 + rep;            // 0..15
            int rb = c >> 1, kt = c & 1;    // rowblk/colblk 0..7, ktile-in-step 0..1
            size_t go = ((size_t)rb * 32 + (size_t)it * 2 + kt) * 512;
            async16(aG + go, &lsA[c * 512 + lane * 8]);
            async16(bG + go, &lsB[c * 512 + lane * 8]);
        }
        __syncthreads();                    // vmcnt drain + all-waves staged

        bf16x8 ca[2][4], cb[2][4];
#pragma unroll
        for (int ks = 0; ks < 2; ++ks)
#pragma unroll
            for (int t = 0; t < 4; ++t) {
                ca[ks][t] = *(const bf16x8*)&lsA[((wr * 4 + t) * 2 + ks) * 512 + lane * 8];
                cb[ks][t] = *(const bf16x8*)&lsB[((wc * 4 + t) * 2 + ks) * 512 + lane * 8];
            }
#pragma unroll
        for (int ks = 0; ks < 2; ++ks)
#pragma unroll
            for (int mt = 0; mt < 4; ++mt)
#pragma unroll
                for (int nt = 0; nt < 4; ++nt)
                    acc[mt][nt] = __builtin_amdgcn_mfma_f32_16x16x32_bf16(ca[ks][mt], cb[ks][nt], acc[mt][nt], 0, 0, 0);
        __syncthreads();                    // all reads done before next stage overwrites
    }

    if (!OUTF32 && z == 2) {
        // V slice: write V^T f16 directly: Vt[(b*NH+h)*DH + d][s]  (= b*1024 + col)
#pragma unroll
        for (int mt = 0; mt < 4; ++mt) {
            int row = m0 + wr * 64 + mt * 16 + quad * 4;   // s0 (r=0..3 consecutive)
            int b = row >> 11, s = row & (SEQ - 1);
#pragma unroll
            for (int nt = 0; nt < 4; ++nt) {
                int col = n0 + wc * 64 + nt * 16 + lm;     // h*64+d
                uint2 pk;
                pk.x = __builtin_bit_cast(u32, __builtin_amdgcn_cvt_pkrtz(acc[mt][nt][0], acc[mt][nt][1]));
                pk.y = __builtin_bit_cast(u32, __builtin_amdgcn_cvt_pkrtz(acc[mt][nt][2], acc[mt][nt][3]));
                *(uint2*)&vtout[((size_t)b * NH * DH + (size_t)col) * SEQ + s] = pk;
            }
        }
        return;
    }

    const bool rope = OUTF32 ? false : (((ropeMask >> z) & 1) != 0);
    const float osc = (!OUTF32 && z == 0) ? QSCALE : 1.0f;

#pragma unroll
    for (int mt = 0; mt < 4; ++mt)
#pragma unroll
        for (int r = 0; r < 4; ++r) {
            int row = m0 + wr * 64 + mt * 16 + quad * 4 + r;
#pragma unroll
            for (int nt = 0; nt < 4; ++nt) {
                int col = n0 + wc * 64 + nt * 16 + lm;
                float v  = acc[mt][nt][r];
                if (rope) {
                    float pv = __shfl_xor(v, 1);
                    float2 cs = ropetab[(row & (SEQ - 1)) * 32 + ((col & 63) >> 1)];
                    v = (lm & 1) ? fmaf(pv, cs.y, v * cs.x) : fmaf(v, cs.x, -pv * cs.y);
                }
                v *= osc;
                if (OUTF32) {
                    outf[(size_t)row * DM + col] = v;
                } else {
                    float hv = __shfl_xor(v, 1);
                    if (!(lm & 1)) {
                        u32 pk = (u32)f2bf(v) | ((u32)f2bf(hv) << 16);
                        *(u32*)&outbf[(size_t)z * ((size_t)MM * DM) + (size_t)row * DM + col] = pk;
                    }
                }
            }
        }
}

// ---------------- causal flash attention, S^T formulation, double-buffered ----------
// q-tile 128, 8 waves x 16 q-rows; k-tile 128; P^T in registers; V^T f16.
// Epilogue writes AO in shuffled-fragment layout (for the no-LDS Wo GEMM).
__global__ __launch_bounds__(512) void attn_kernel(const u16* __restrict__ Q,
                                                   const u16* __restrict__ K,
                                                   const _Float16* __restrict__ Vt,
                                                   u16* __restrict__ AO) {
    const int u  = blockIdx.x;
    const int qt = (u < 256) ? (15 - (u >> 5)) : ((u >> 5) - 8);
    const int bh = u & 31;
    const int b  = bh >> 4, h = bh & 15;
    const int q0 = qt * 128;
    const int tid = threadIdx.x, w = tid >> 6, lane = tid & 63;
    const int lm = lane & 15, quad = lane >> 4;

    __shared__ __align__(16) u16      lsK[2][128 * 64];   // [key][dim], col-swizzled
    __shared__ __align__(16) _Float16 lsV[2][64 * 128];   // [dim][key], 16B-block swizzled

    bf16x8 qb[2];
#pragma unroll
    for (int ks = 0; ks < 2; ++ks)
        qb[ks] = *(const bf16x8*)
            &Q[(size_t)(b * SEQ + q0 + w * 16 + lm) * DM + h * DH + ks * 32 + quad * 8];

    const floatx4 z4 = {0.f, 0.f, 0.f, 0.f};
    floatx4 o[4];                 // O^T[d][q]: d = dt*16+quad*4+r, q = lm
#pragma unroll
    for (int dt = 0; dt < 4; ++dt) o[dt] = z4;
    float lsum = 0.f;

    const int qloc = w * 16 + lm;

    auto stageKV = [&](int buf, int kt) {
#pragma unroll
        for (int rep = 0; rep < 2; ++rep) {
            int f = rep * 512 + tid;
            int krow = f >> 3, kcb = (f & 7) ^ (krow & 7);
            async16(&K[(size_t)(b * SEQ + kt * 128 + krow) * DM + h * DH + kcb * 8],
                    &lsK[buf][f * 8]);
            int d = f >> 4, gbs = (f & 15) ^ ((d >> 1) & 7);
            async16(&Vt[(size_t)(bh * DH + d) * SEQ + kt * 128 + gbs * 8],
                    &lsV[buf][f * 8]);
        }
    };

    stageKV(0, 0);
    for (int kt = 0; kt <= qt; ++kt) {
        __syncthreads();
        if (kt < qt) stageKV((kt + 1) & 1, kt + 1);
        const u16*      Lk = lsK[kt & 1];
        const _Float16* Lv = lsV[kt & 1];

        floatx4 s4[8];
#pragma unroll
        for (int st = 0; st < 8; ++st) s4[st] = z4;
#pragma unroll
        for (int ks = 0; ks < 2; ++ks) {
            const int cbl = ((ks * 4 + quad) ^ (lm & 7)) * 8;
#pragma unroll
            for (int st = 0; st < 8; ++st) {
                bf16x8 ka = *(const bf16x8*)&Lk[(st * 16 + lm) * 64 + cbl];
                s4[st] = __builtin_amdgcn_mfma_f32_16x16x32_bf16(ka, qb[ks], s4[st], 0, 0, 0);
            }
        }

        halfx4 pb[8];
        const bool diag = (kt == qt);
#pragma unroll
        for (int st = 0; st < 8; ++st) {
#pragma unroll
            for (int r = 0; r < 4; ++r) {
                float v = s4[st][r];
                if (diag) {
                    int keyloc = st * 16 + quad * 4 + r;
                    if (keyloc > qloc) v = -1e30f;
                }
                v = exp2f(v);
                lsum += v;
                s4[st][r] = v;
            }
            uintx2 pk2;
            pk2.x = __builtin_bit_cast(u32, __builtin_amdgcn_cvt_pkrtz(s4[st][0], s4[st][1]));
            pk2.y = __builtin_bit_cast(u32, __builtin_amdgcn_cvt_pkrtz(s4[st][2], s4[st][3]));
            pb[st] = __builtin_bit_cast(halfx4, pk2);
        }

#pragma unroll
        for (int st = 0; st < 8; ++st) {
#pragma unroll
            for (int dt = 0; dt < 4; ++dt) {
                int drow = dt * 16 + lm;
                int sbs = (st * 2 + (quad >> 1)) ^ ((drow >> 1) & 7);
                halfx4 va = *(const halfx4*)&Lv[drow * 128 + sbs * 8 + (quad & 1) * 4];
                o[dt] = __builtin_amdgcn_mfma_f32_16x16x16f16(va, pb[st], o[dt], 0, 0, 0);
            }
        }
    }

    // row-sum across the 4 quads holding q = lm
    lsum += __shfl_xor(lsum, 16);
    lsum += __shfl_xor(lsum, 32);
    float rl = 1.0f / lsum;

    // epilogue: O^T (reg) -> LDS (swizzled natural [q][d]) -> shuffled-frag AO store
    __syncthreads();                       // all waves done with lsK/lsV
    u16* eb = (u16*)&lsK[0][0];            // 128x64 bf16 = 16 KB
    const int q = w * 16 + lm;
#pragma unroll
    for (int dt = 0; dt < 4; ++dt) {
        uint2 pk;
        pk.x = (u32)f2bf(o[dt][0] * rl) | ((u32)f2bf(o[dt][1] * rl) << 16);
        pk.y = (u32)f2bf(o[dt][2] * rl) | ((u32)f2bf(o[dt][3] * rl) << 16);
        int ch = (dt * 2 + (quad >> 1)) ^ (lm & 7);
        *(uint2*)&eb[q * 64 + ch * 8 + (quad & 1) * 4] = pk;
    }
    __syncthreads();
    const size_t rowblk = (size_t)((b * SEQ + q0) >> 4) + w;
#pragma unroll
    for (int kt = 0; kt < 2; ++kt) {
        uint4 v = *(const uint4*)&eb[(w * 16 + lm) * 64 + ((kt * 4 + quad) ^ (lm & 7)) * 8];
        *(uint4*)&AO[(rowblk * 32 + (h * 2 + kt)) * 512 + lane * 8] = v;
    }
}

extern "C" void kernel_launch(void* const* d_in, const int* in_sizes, int n_in,
                              void* d_out, int out_size, void* d_ws, size_t ws_size,
                              hipStream_t stream) {
    const float* x   = (const float*)d_in[0];
    const int*   pos = (const int*)d_in[1];
    float* out = (float*)d_out;

    u16* ws = (u16*)d_ws;
    const size_t MD = (size_t)MM * DM;
    const size_t DD = (size_t)DM * DM;
    u16* Xsh = ws;                        // shuffled X; dead after QKV -> reused as AOsh
    u16* Wsh = ws + MD;                   // 4 shuffled weights (q,k,v,o)
    u16* Qbf = ws + MD + 4 * DD;          // natural layouts
    u16* Kbf = Qbf + MD;
    u16* VtB = Kbf + MD;                  // f16 V^T (written by QKV z==2 epilogue)
    float2* ropetab = (float2*)(VtB + MD);
    _Float16* Vt = (_Float16*)VtB;
    u16* AOsh = Xsh;

    // prep: bf16 shuffled X + 4 W, RoPE table (one launch)
    prep_kernel<<<dim3(128, 16), 256, 0, stream>>>(
        x, (const float*)d_in[2], (const float*)d_in[3], (const float*)d_in[4],
        (const float*)d_in[5], Xsh, Wsh, pos, ropetab);

    // Q/K/V projections; RoPE fused on Q,K; softmax scale folded into Q; V^T written directly
    gemm_ls<false><<<dim3(32, 8, 3), 256, 0, stream>>>(
        Xsh, Wsh, Qbf, nullptr, Vt, ropetab, 0x3);

    // causal flash attention (writes AO in shuffled-frag layout)
    attn_kernel<<<dim3(512), 512, 0, stream>>>(Qbf, Kbf, Vt, AOsh);

    // output projection -> fp32 d_out
    gemm_ls<true><<<dim3(32, 8, 1), 256, 0, stream>>>(
        AOsh, Wsh + 3 * DD, nullptr, out, nullptr, nullptr, 0);
}

// Round 2
// 192.238 us; speedup vs baseline: 1.0647x; 1.0647x over previous
//
#include <hip/hip_runtime.h>
#include <math.h>

typedef unsigned short u16;
typedef unsigned int   u32;
typedef __attribute__((ext_vector_type(8))) short bf16x8;
typedef __attribute__((ext_vector_type(4))) float floatx4;
typedef __attribute__((ext_vector_type(4))) _Float16 halfx4;
typedef __attribute__((ext_vector_type(2))) unsigned int uintx2;

// B=2, S=2048, D=1024, H=16, Dh=64, M=B*S=4096
#define SEQ 2048
#define DM  1024
#define NH  16
#define DH  64
#define MM  4096
#define QSCALE 0.18033688011112042f   // 0.125 * log2(e), folded into Q

__device__ __forceinline__ u16 f2bf(float f) {
    u32 u = __builtin_bit_cast(u32, f);
    u += 0x7fffu + ((u >> 16) & 1u);
    return (u16)(u >> 16);
}

__device__ __forceinline__ void async16(const void* g, void* l) {
    __builtin_amdgcn_global_load_lds(
        (const __attribute__((address_space(1))) void*)g,
        (__attribute__((address_space(3))) void*)l, 16, 0, 0);
}

// ---------------- prep: fp32 -> bf16 shuffled layout + RoPE table -------------------
// Shuffled layout: tile (rowblk=row/16, ktile=col/32); element [m=lm][k=quad*8+j]
// stored flat at (rowblk*32 + ktile)*512 + lane*8 + j. One dwordx4/lane per fragment.
// First 256 linear blocks additionally fill the RoPE table (2048x32 float2).
__global__ __launch_bounds__(256) void prep_kernel(const float* __restrict__ x,
                                                   const float* __restrict__ w0,
                                                   const float* __restrict__ w1,
                                                   const float* __restrict__ w2,
                                                   const float* __restrict__ w3,
                                                   u16* __restrict__ Xsh,
                                                   u16* __restrict__ Wsh,
                                                   const int* __restrict__ pos,
                                                   float2* __restrict__ tab) {
    const int bid = blockIdx.x, cb = blockIdx.y, tid = threadIdx.x;

    // RoPE table side-job
    int lin = bid * 16 + cb;
    if (lin < 256) {
        int i = lin * 256 + tid;       // 65536 = 2048*32
        int p = i >> 5, d2 = i & 31;
        float freq = __expf(-(float)d2 * (9.2103403719761836f / 32.0f));
        float sv, cv;
        sincosf((float)pos[p] * freq, &sv, &cv);
        tab[i] = make_float2(cv, sv);
    }

    const float* src; u16* dst; int row0;
    if (bid < 64) { src = x; dst = Xsh; row0 = bid * 64; }
    else {
        int wi = (bid - 64) >> 4;
        src = (wi == 0) ? w0 : (wi == 1) ? w1 : (wi == 2) ? w2 : w3;
        dst = Wsh + (size_t)wi * DM * DM;
        row0 = ((bid - 64) & 15) * 64;
    }
    __shared__ __align__(16) u16 t[64 * 64];   // 8-elem chunks XOR-swizzled by row&7
#pragma unroll
    for (int rep = 0; rep < 4; ++rep) {
        int f = rep * 256 + tid;
        int r = f >> 4, c4 = f & 15;
        float4 v = *(const float4*)&src[(size_t)(row0 + r) * DM + cb * 64 + c4 * 4];
        uint2 pk;
        pk.x = (u32)f2bf(v.x) | ((u32)f2bf(v.y) << 16);
        pk.y = (u32)f2bf(v.z) | ((u32)f2bf(v.w) << 16);
        int ch = (c4 >> 1) ^ (r & 7);
        *(uint2*)&t[r * 64 + ch * 8 + (c4 & 1) * 4] = pk;
    }
    __syncthreads();
#pragma unroll
    for (int rep = 0; rep < 2; ++rep) {
        int s = rep * 256 + tid;
        int tile = s >> 6, l = s & 63;
        int mt = tile >> 1, kt = tile & 1, lm = l & 15, quad = l >> 4;
        int m = mt * 16 + lm;
        uint4 v = *(const uint4*)&t[m * 64 + ((kt * 4 + quad) ^ (m & 7)) * 8];
        size_t rowblk = (size_t)(row0 >> 4) + mt;
        size_t ktile  = cb * 2 + kt;
        *(uint4*)&dst[(rowblk * 32 + ktile) * 512 + l * 8] = v;
    }
}

// ---------------- fused-z NT GEMM, LDS double-buffered, stage-ahead -----------------
// C_z[M,1024] = A * W_z^T for z in [0,NZ). Block tile 64 rows x 128 cols, 4 waves,
// wave w owns cols [n0+w*32, +32). BK=32 (1 ktile/step), 32 K-steps.
// Both operands staged via global_load_lds into DOUBLE-buffered LDS; stage for step
// it+1 is issued BEFORE computing step it, so the vmcnt drain at the (single)
// end-of-iter barrier lands after 24 (NZ=3) MFMAs of latency hiding.
// A is loaded once per block (shared by 4 waves); with NZ=3 each staged byte feeds
// 3x the MFMAs (Q,K,V share A). Epilogues: RoPE on z<2, QSCALE on z==0, V^T f16
// for z==2; OUTF32 path (Wo) writes fp32.
template<int NZ, bool OUTF32>
__global__ __launch_bounds__(256, 2) void gemm_f(const u16* __restrict__ Ash,
                                                 const u16* __restrict__ Wbase,
                                                 u16* __restrict__ outbf,
                                                 float* __restrict__ outf,
                                                 _Float16* __restrict__ vtout,
                                                 const float2* __restrict__ ropetab) {
    const int m0 = blockIdx.x * 64, n0 = blockIdx.y * 128;
    const int tid = threadIdx.x, lane = tid & 63, w = tid >> 6;
    const int lm = lane & 15, quad = lane >> 4;
    const int rb0 = m0 >> 4;        // 4 rowblks per block
    const int cb0 = n0 >> 4;        // 8 colblks per block

    __shared__ __align__(16) u16 lsA[2][4 * 512];        // 2 x 4KB
    __shared__ __align__(16) u16 lsB[2][NZ * 8 * 512];   // 2 x NZ*8KB

    // per-wave staging sources (chunk stride between ktiles = 512 elems)
    const u16* aSrc = Ash + ((size_t)(rb0 + w) * 32) * 512 + lane * 8;
    constexpr int NPW = NZ * 2;     // B pieces per wave (NZ*8 pieces / 4 waves)
    const u16* bSrc[NPW];
#pragma unroll
    for (int j = 0; j < NPW; ++j) {
        int p = w * NPW + j, z = p >> 3, cb8 = p & 7;
        bSrc[j] = Wbase + (size_t)z * (DM * DM)
                + ((size_t)(cb0 + cb8) * 32) * 512 + lane * 8;
    }

    auto stage = [&](int buf, int it) {
        async16(aSrc + (size_t)it * 512, &lsA[buf][w * 512 + lane * 8]);
#pragma unroll
        for (int j = 0; j < NPW; ++j)
            async16(bSrc[j] + (size_t)it * 512,
                    &lsB[buf][(w * NPW + j) * 512 + lane * 8]);
    };

    floatx4 acc[NZ][4][2];
    const floatx4 z4 = {0.f, 0.f, 0.f, 0.f};
#pragma unroll
    for (int z = 0; z < NZ; ++z)
#pragma unroll
        for (int mt = 0; mt < 4; ++mt)
#pragma unroll
            for (int nt = 0; nt < 2; ++nt) acc[z][mt][nt] = z4;

    stage(0, 0);
    __syncthreads();

#pragma unroll 2
    for (int it = 0; it < 32; ++it) {
        if (it < 31) stage((it + 1) & 1, it + 1);   // stage-ahead (hidden under MFMAs)
        const u16* La = &lsA[it & 1][0];
        const u16* Lb = &lsB[it & 1][0];
        bf16x8 a[4], b[NZ][2];
#pragma unroll
        for (int mt = 0; mt < 4; ++mt)
            a[mt] = *(const bf16x8*)&La[mt * 512 + lane * 8];
#pragma unroll
        for (int z = 0; z < NZ; ++z)
#pragma unroll
            for (int nt = 0; nt < 2; ++nt)
                b[z][nt] = *(const bf16x8*)&Lb[(z * 8 + w * 2 + nt) * 512 + lane * 8];
#pragma unroll
        for (int z = 0; z < NZ; ++z)
#pragma unroll
            for (int mt = 0; mt < 4; ++mt)
#pragma unroll
                for (int nt = 0; nt < 2; ++nt)
                    acc[z][mt][nt] = __builtin_amdgcn_mfma_f32_16x16x32_bf16(
                        a[mt], b[z][nt], acc[z][mt][nt], 0, 0, 0);
        __syncthreads();    // vmcnt drain (stage it+1 landed) + LDS read/write fence
    }

#pragma unroll
    for (int z = 0; z < NZ; ++z) {
        if (!OUTF32 && NZ == 3 && z == 2) {
            // V slice: write V^T f16 directly: Vt[(b*NH+h)*DH + d][s]
#pragma unroll
            for (int mt = 0; mt < 4; ++mt) {
                int row = m0 + mt * 16 + quad * 4;          // s0 (r=0..3 consecutive)
                int b = row >> 11, s = row & (SEQ - 1);
#pragma unroll
                for (int nt = 0; nt < 2; ++nt) {
                    int col = n0 + w * 32 + nt * 16 + lm;   // h*64+d
                    uint2 pk;
                    pk.x = __builtin_bit_cast(u32, __builtin_amdgcn_cvt_pkrtz(acc[z][mt][nt][0], acc[z][mt][nt][1]));
                    pk.y = __builtin_bit_cast(u32, __builtin_amdgcn_cvt_pkrtz(acc[z][mt][nt][2], acc[z][mt][nt][3]));
                    *(uint2*)&vtout[((size_t)b * NH * DH + (size_t)col) * SEQ + s] = pk;
                }
            }
            continue;
        }
        const bool rope = !OUTF32;                 // z in {0,1} here
        const float osc = (!OUTF32 && z == 0) ? QSCALE : 1.0f;
#pragma unroll
        for (int mt = 0; mt < 4; ++mt)
#pragma unroll
            for (int r = 0; r < 4; ++r) {
                int row = m0 + mt * 16 + quad * 4 + r;
#pragma unroll
                for (int nt = 0; nt < 2; ++nt) {
                    int col = n0 + w * 32 + nt * 16 + lm;
                    float v  = acc[z][mt][nt][r];
                    if (rope) {
                        float pv = __shfl_xor(v, 1);
                        float2 cs = ropetab[(row & (SEQ - 1)) * 32 + ((col & 63) >> 1)];
                        v = (lm & 1) ? fmaf(pv, cs.y, v * cs.x) : fmaf(v, cs.x, -pv * cs.y);
                    }
                    v *= osc;
                    if (OUTF32) {
                        outf[(size_t)row * DM + col] = v;
                    } else {
                        float hv = __shfl_xor(v, 1);
                        if (!(lm & 1)) {
                            u32 pk = (u32)f2bf(v) | ((u32)f2bf(hv) << 16);
                            *(u32*)&outbf[(size_t)z * ((size_t)MM * DM) + (size_t)row * DM + col] = pk;
                        }
                    }
                }
            }
    }
}

// ---------------- causal flash attention, S^T formulation, double-buffered ----------
// q-tile 128, 8 waves x 16 q-rows; k-tile 128; P^T in registers; V^T f16.
// Epilogue writes AO in shuffled-fragment layout (for the no-LDS Wo GEMM).
__global__ __launch_bounds__(512) void attn_kernel(const u16* __restrict__ Q,
                                                   const u16* __restrict__ K,
                                                   const _Float16* __restrict__ Vt,
                                                   u16* __restrict__ AO) {
    const int u  = blockIdx.x;
    const int qt = (u < 256) ? (15 - (u >> 5)) : ((u >> 5) - 8);
    const int bh = u & 31;
    const int b  = bh >> 4, h = bh & 15;
    const int q0 = qt * 128;
    const int tid = threadIdx.x, w = tid >> 6, lane = tid & 63;
    const int lm = lane & 15, quad = lane >> 4;

    __shared__ __align__(16) u16      lsK[2][128 * 64];   // [key][dim], col-swizzled
    __shared__ __align__(16) _Float16 lsV[2][64 * 128];   // [dim][key], 16B-block swizzled

    bf16x8 qb[2];
#pragma unroll
    for (int ks = 0; ks < 2; ++ks)
        qb[ks] = *(const bf16x8*)
            &Q[(size_t)(b * SEQ + q0 + w * 16 + lm) * DM + h * DH + ks * 32 + quad * 8];

    const floatx4 z4 = {0.f, 0.f, 0.f, 0.f};
    floatx4 o[4];                 // O^T[d][q]: d = dt*16+quad*4+r, q = lm
#pragma unroll
    for (int dt = 0; dt < 4; ++dt) o[dt] = z4;
    float lsum = 0.f;

    const int qloc = w * 16 + lm;

    auto stageKV = [&](int buf, int kt) {
#pragma unroll
        for (int rep = 0; rep < 2; ++rep) {
            int f = rep * 512 + tid;
            int krow = f >> 3, kcb = (f & 7) ^ (krow & 7);
            async16(&K[(size_t)(b * SEQ + kt * 128 + krow) * DM + h * DH + kcb * 8],
                    &lsK[buf][f * 8]);
            int d = f >> 4, gbs = (f & 15) ^ ((d >> 1) & 7);
            async16(&Vt[(size_t)(bh * DH + d) * SEQ + kt * 128 + gbs * 8],
                    &lsV[buf][f * 8]);
        }
    };

    stageKV(0, 0);
    for (int kt = 0; kt <= qt; ++kt) {
        __syncthreads();
        if (kt < qt) stageKV((kt + 1) & 1, kt + 1);
        const u16*      Lk = lsK[kt & 1];
        const _Float16* Lv = lsV[kt & 1];

        floatx4 s4[8];
#pragma unroll
        for (int st = 0; st < 8; ++st) s4[st] = z4;
#pragma unroll
        for (int ks = 0; ks < 2; ++ks) {
            const int cbl = ((ks * 4 + quad) ^ (lm & 7)) * 8;
#pragma unroll
            for (int st = 0; st < 8; ++st) {
                bf16x8 ka = *(const bf16x8*)&Lk[(st * 16 + lm) * 64 + cbl];
                s4[st] = __builtin_amdgcn_mfma_f32_16x16x32_bf16(ka, qb[ks], s4[st], 0, 0, 0);
            }
        }

        halfx4 pb[8];
        const bool diag = (kt == qt);
#pragma unroll
        for (int st = 0; st < 8; ++st) {
#pragma unroll
            for (int r = 0; r < 4; ++r) {
                float v = s4[st][r];
                if (diag) {
                    int keyloc = st * 16 + quad * 4 + r;
                    if (keyloc > qloc) v = -1e30f;
                }
                v = exp2f(v);
                lsum += v;
                s4[st][r] = v;
            }
            uintx2 pk2;
            pk2.x = __builtin_bit_cast(u32, __builtin_amdgcn_cvt_pkrtz(s4[st][0], s4[st][1]));
            pk2.y = __builtin_bit_cast(u32, __builtin_amdgcn_cvt_pkrtz(s4[st][2], s4[st][3]));
            pb[st] = __builtin_bit_cast(halfx4, pk2);
        }

#pragma unroll
        for (int st = 0; st < 8; ++st) {
#pragma unroll
            for (int dt = 0; dt < 4; ++dt) {
                int drow = dt * 16 + lm;
                int sbs = (st * 2 + (quad >> 1)) ^ ((drow >> 1) & 7);
                halfx4 va = *(const halfx4*)&Lv[drow * 128 + sbs * 8 + (quad & 1) * 4];
                o[dt] = __builtin_amdgcn_mfma_f32_16x16x16f16(va, pb[st], o[dt], 0, 0, 0);
            }
        }
    }

    // row-sum across the 4 quads holding q = lm
    lsum += __shfl_xor(lsum, 16);
    lsum += __shfl_xor(lsum, 32);
    float rl = 1.0f / lsum;

    // epilogue: O^T (reg) -> LDS (swizzled natural [q][d]) -> shuffled-frag AO store
    __syncthreads();                       // all waves done with lsK/lsV
    u16* eb = (u16*)&lsK[0][0];            // 128x64 bf16 = 16 KB
    const int q = w * 16 + lm;
#pragma unroll
    for (int dt = 0; dt < 4; ++dt) {
        uint2 pk;
        pk.x = (u32)f2bf(o[dt][0] * rl) | ((u32)f2bf(o[dt][1] * rl) << 16);
        pk.y = (u32)f2bf(o[dt][2] * rl) | ((u32)f2bf(o[dt][3] * rl) << 16);
        int ch = (dt * 2 + (quad >> 1)) ^ (lm & 7);
        *(uint2*)&eb[q * 64 + ch * 8 + (quad & 1) * 4] = pk;
    }
    __syncthreads();
    const size_t rowblk = (size_t)((b * SEQ + q0) >> 4) + w;
#pragma unroll
    for (int kt = 0; kt < 2; ++kt) {
        uint4 v = *(const uint4*)&eb[(w * 16 + lm) * 64 + ((kt * 4 + quad) ^ (lm & 7)) * 8];
        *(uint4*)&AO[(rowblk * 32 + (h * 2 + kt)) * 512 + lane * 8] = v;
    }
}

extern "C" void kernel_launch(void* const* d_in, const int* in_sizes, int n_in,
                              void* d_out, int out_size, void* d_ws, size_t ws_size,
                              hipStream_t stream) {
    const float* x   = (const float*)d_in[0];
    const int*   pos = (const int*)d_in[1];
    float* out = (float*)d_out;

    u16* ws = (u16*)d_ws;
    const size_t MD = (size_t)MM * DM;
    const size_t DD = (size_t)DM * DM;
    u16* Xsh = ws;                        // shuffled X; dead after QKV -> reused as AOsh
    u16* Wsh = ws + MD;                   // 4 shuffled weights (q,k,v,o)
    u16* Qbf = ws + MD + 4 * DD;          // natural layouts
    u16* Kbf = Qbf + MD;
    u16* VtB = Kbf + MD;                  // f16 V^T (written by QKV z==2 epilogue)
    float2* ropetab = (float2*)(VtB + MD);
    _Float16* Vt = (_Float16*)VtB;
    u16* AOsh = Xsh;

    // prep: bf16 shuffled X + 4 W, RoPE table (one launch)
    prep_kernel<<<dim3(128, 16), 256, 0, stream>>>(
        x, (const float*)d_in[2], (const float*)d_in[3], (const float*)d_in[4],
        (const float*)d_in[5], Xsh, Wsh, pos, ropetab);

    // fused Q/K/V projections (z-fused: A staged once, 3x MFMA per staged byte);
    // RoPE fused on Q,K; softmax scale folded into Q; V^T f16 written directly
    gemm_f<3, false><<<dim3(64, 8), 256, 0, stream>>>(
        Xsh, Wsh, Qbf, nullptr, Vt, ropetab);

    // causal flash attention (writes AO in shuffled-frag layout)
    attn_kernel<<<dim3(512), 512, 0, stream>>>(Qbf, Kbf, Vt, AOsh);

    // output projection -> fp32 d_out
    gemm_f<1, true><<<dim3(64, 8), 256, 0, stream>>>(
        AOsh, Wsh + 3 * DD, nullptr, out, nullptr, ropetab);
}

// Round 3
// 187.295 us; speedup vs baseline: 1.0928x; 1.0264x over previous
//
#include <hip/hip_runtime.h>
#include <math.h>

typedef unsigned short u16;
typedef unsigned int   u32;
typedef __attribute__((ext_vector_type(8))) short bf16x8;
typedef __attribute__((ext_vector_type(4))) float floatx4;
typedef __attribute__((ext_vector_type(4))) _Float16 halfx4;
typedef __attribute__((ext_vector_type(2))) unsigned int uintx2;

// B=2, S=2048, D=1024, H=16, Dh=64, M=B*S=4096
#define SEQ 2048
#define DM  1024
#define NH  16
#define DH  64
#define MM  4096
#define QSCALE 0.18033688011112042f   // 0.125 * log2(e), folded into Q

__device__ __forceinline__ u16 f2bf(float f) {
    u32 u = __builtin_bit_cast(u32, f);
    u += 0x7fffu + ((u >> 16) & 1u);
    return (u16)(u >> 16);
}

__device__ __forceinline__ void async16(const void* g, void* l) {
    __builtin_amdgcn_global_load_lds(
        (const __attribute__((address_space(1))) void*)g,
        (__attribute__((address_space(3))) void*)l, 16, 0, 0);
}

// ---------------- prep: fp32 -> bf16 shuffled layout + RoPE table -------------------
// Shuffled layout: tile (rowblk=row/16, ktile=col/32); element [m=lm][k=quad*8+j]
// stored flat at (rowblk*32 + ktile)*512 + lane*8 + j. One dwordx4/lane per fragment.
// First 256 linear blocks additionally fill the RoPE table (2048x32 float2).
__global__ __launch_bounds__(256) void prep_kernel(const float* __restrict__ x,
                                                   const float* __restrict__ w0,
                                                   const float* __restrict__ w1,
                                                   const float* __restrict__ w2,
                                                   const float* __restrict__ w3,
                                                   u16* __restrict__ Xsh,
                                                   u16* __restrict__ Wsh,
                                                   const int* __restrict__ pos,
                                                   float2* __restrict__ tab) {
    const int bid = blockIdx.x, cb = blockIdx.y, tid = threadIdx.x;

    // RoPE table side-job
    int lin = bid * 16 + cb;
    if (lin < 256) {
        int i = lin * 256 + tid;       // 65536 = 2048*32
        int p = i >> 5, d2 = i & 31;
        float freq = __expf(-(float)d2 * (9.2103403719761836f / 32.0f));
        float sv, cv;
        sincosf((float)pos[p] * freq, &sv, &cv);
        tab[i] = make_float2(cv, sv);
    }

    const float* src; u16* dst; int row0;
    if (bid < 64) { src = x; dst = Xsh; row0 = bid * 64; }
    else {
        int wi = (bid - 64) >> 4;
        src = (wi == 0) ? w0 : (wi == 1) ? w1 : (wi == 2) ? w2 : w3;
        dst = Wsh + (size_t)wi * DM * DM;
        row0 = ((bid - 64) & 15) * 64;
    }
    __shared__ __align__(16) u16 t[64 * 64];   // 8-elem chunks XOR-swizzled by row&7
#pragma unroll
    for (int rep = 0; rep < 4; ++rep) {
        int f = rep * 256 + tid;
        int r = f >> 4, c4 = f & 15;
        float4 v = *(const float4*)&src[(size_t)(row0 + r) * DM + cb * 64 + c4 * 4];
        uint2 pk;
        pk.x = (u32)f2bf(v.x) | ((u32)f2bf(v.y) << 16);
        pk.y = (u32)f2bf(v.z) | ((u32)f2bf(v.w) << 16);
        int ch = (c4 >> 1) ^ (r & 7);
        *(uint2*)&t[r * 64 + ch * 8 + (c4 & 1) * 4] = pk;
    }
    __syncthreads();
#pragma unroll
    for (int rep = 0; rep < 2; ++rep) {
        int s = rep * 256 + tid;
        int tile = s >> 6, l = s & 63;
        int mt = tile >> 1, kt = tile & 1, lm = l & 15, quad = l >> 4;
        int m = mt * 16 + lm;
        uint4 v = *(const uint4*)&t[m * 64 + ((kt * 4 + quad) ^ (m & 7)) * 8];
        size_t rowblk = (size_t)(row0 >> 4) + mt;
        size_t ktile  = cb * 2 + kt;
        *(uint4*)&dst[(rowblk * 32 + ktile) * 512 + l * 8] = v;
    }
}

// ---------------- fused-z NT GEMM, LDS double-buffered, stage-ahead -----------------
// C_z[M,1024] = A * W_z^T for z in [0,NZ). Block tile 64 rows x 128 cols, 4 waves,
// wave w owns cols [n0+w*32, +32). BK=32 (1 ktile/step), 32 K-steps.
// Both operands staged via global_load_lds into DOUBLE-buffered LDS; stage for step
// it+1 is issued BEFORE computing step it, so the vmcnt drain at the (single)
// end-of-iter barrier lands after 24 (NZ=3) MFMAs of latency hiding.
// A is loaded once per block (shared by 4 waves); with NZ=3 each staged byte feeds
// 3x the MFMAs (Q,K,V share A). Epilogues: RoPE on z<2, QSCALE on z==0, V^T f16
// for z==2; OUTF32 path (Wo) writes fp32.
template<int NZ, bool OUTF32>
__global__ __launch_bounds__(256, 2) void gemm_f(const u16* __restrict__ Ash,
                                                 const u16* __restrict__ Wbase,
                                                 u16* __restrict__ outbf,
                                                 float* __restrict__ outf,
                                                 _Float16* __restrict__ vtout,
                                                 const float2* __restrict__ ropetab) {
    const int m0 = blockIdx.x * 64, n0 = blockIdx.y * 128;
    const int tid = threadIdx.x, lane = tid & 63, w = tid >> 6;
    const int lm = lane & 15, quad = lane >> 4;
    const int rb0 = m0 >> 4;        // 4 rowblks per block
    const int cb0 = n0 >> 4;        // 8 colblks per block

    __shared__ __align__(16) u16 lsA[2][4 * 512];        // 2 x 4KB
    __shared__ __align__(16) u16 lsB[2][NZ * 8 * 512];   // 2 x NZ*8KB

    // per-wave staging sources (chunk stride between ktiles = 512 elems)
    const u16* aSrc = Ash + ((size_t)(rb0 + w) * 32) * 512 + lane * 8;
    constexpr int NPW = NZ * 2;     // B pieces per wave (NZ*8 pieces / 4 waves)
    const u16* bSrc[NPW];
#pragma unroll
    for (int j = 0; j < NPW; ++j) {
        int p = w * NPW + j, z = p >> 3, cb8 = p & 7;
        bSrc[j] = Wbase + (size_t)z * (DM * DM)
                + ((size_t)(cb0 + cb8) * 32) * 512 + lane * 8;
    }

    auto stage = [&](int buf, int it) {
        async16(aSrc + (size_t)it * 512, &lsA[buf][w * 512 + lane * 8]);
#pragma unroll
        for (int j = 0; j < NPW; ++j)
            async16(bSrc[j] + (size_t)it * 512,
                    &lsB[buf][(w * NPW + j) * 512 + lane * 8]);
    };

    floatx4 acc[NZ][4][2];
    const floatx4 z4 = {0.f, 0.f, 0.f, 0.f};
#pragma unroll
    for (int z = 0; z < NZ; ++z)
#pragma unroll
        for (int mt = 0; mt < 4; ++mt)
#pragma unroll
            for (int nt = 0; nt < 2; ++nt) acc[z][mt][nt] = z4;

    stage(0, 0);
    __syncthreads();

#pragma unroll 2
    for (int it = 0; it < 32; ++it) {
        if (it < 31) stage((it + 1) & 1, it + 1);   // stage-ahead (hidden under MFMAs)
        const u16* La = &lsA[it & 1][0];
        const u16* Lb = &lsB[it & 1][0];
        bf16x8 a[4], b[NZ][2];
#pragma unroll
        for (int mt = 0; mt < 4; ++mt)
            a[mt] = *(const bf16x8*)&La[mt * 512 + lane * 8];
#pragma unroll
        for (int z = 0; z < NZ; ++z)
#pragma unroll
            for (int nt = 0; nt < 2; ++nt)
                b[z][nt] = *(const bf16x8*)&Lb[(z * 8 + w * 2 + nt) * 512 + lane * 8];
#pragma unroll
        for (int z = 0; z < NZ; ++z)
#pragma unroll
            for (int mt = 0; mt < 4; ++mt)
#pragma unroll
                for (int nt = 0; nt < 2; ++nt)
                    acc[z][mt][nt] = __builtin_amdgcn_mfma_f32_16x16x32_bf16(
                        a[mt], b[z][nt], acc[z][mt][nt], 0, 0, 0);
        __syncthreads();    // vmcnt drain (stage it+1 landed) + LDS read/write fence
    }

#pragma unroll
    for (int z = 0; z < NZ; ++z) {
        if (!OUTF32 && NZ == 3 && z == 2) {
            // V slice: write V^T f16 directly: Vt[(b*NH+h)*DH + d][s]
#pragma unroll
            for (int mt = 0; mt < 4; ++mt) {
                int row = m0 + mt * 16 + quad * 4;          // s0 (r=0..3 consecutive)
                int b = row >> 11, s = row & (SEQ - 1);
#pragma unroll
                for (int nt = 0; nt < 2; ++nt) {
                    int col = n0 + w * 32 + nt * 16 + lm;   // h*64+d
                    uint2 pk;
                    pk.x = __builtin_bit_cast(u32, __builtin_amdgcn_cvt_pkrtz(acc[z][mt][nt][0], acc[z][mt][nt][1]));
                    pk.y = __builtin_bit_cast(u32, __builtin_amdgcn_cvt_pkrtz(acc[z][mt][nt][2], acc[z][mt][nt][3]));
                    *(uint2*)&vtout[((size_t)b * NH * DH + (size_t)col) * SEQ + s] = pk;
                }
            }
            continue;
        }
        const bool rope = !OUTF32;                 // z in {0,1} here
        const float osc = (!OUTF32 && z == 0) ? QSCALE : 1.0f;
#pragma unroll
        for (int mt = 0; mt < 4; ++mt)
#pragma unroll
            for (int r = 0; r < 4; ++r) {
                int row = m0 + mt * 16 + quad * 4 + r;
#pragma unroll
                for (int nt = 0; nt < 2; ++nt) {
                    int col = n0 + w * 32 + nt * 16 + lm;
                    float v  = acc[z][mt][nt][r];
                    if (rope) {
                        float pv = __shfl_xor(v, 1);
                        float2 cs = ropetab[(row & (SEQ - 1)) * 32 + ((col & 63) >> 1)];
                        v = (lm & 1) ? fmaf(pv, cs.y, v * cs.x) : fmaf(v, cs.x, -pv * cs.y);
                    }
                    v *= osc;
                    if (OUTF32) {
                        outf[(size_t)row * DM + col] = v;
                    } else {
                        float hv = __shfl_xor(v, 1);
                        if (!(lm & 1)) {
                            u32 pk = (u32)f2bf(v) | ((u32)f2bf(hv) << 16);
                            *(u32*)&outbf[(size_t)z * ((size_t)MM * DM) + (size_t)row * DM + col] = pk;
                        }
                    }
                }
            }
    }
}

// ---------------- causal flash attention, S^T formulation, double-buffered ----------
// q-tile 128, 4 waves x 32 q-rows (2 q-fragments/wave); k-tile 128; P^T in registers;
// V^T f16. LDS-traffic-optimized: ka/va fragments are loaded ONCE per (st,ks)/(st,dt)
// and feed BOTH q-fragments (LDS reads scale as 1/q-rows-per-wave; this is 2x fewer
// than 8 waves x 16 q-rows). Epilogue writes AO in shuffled-fragment layout.
__global__ __launch_bounds__(256, 2) void attn_kernel(const u16* __restrict__ Q,
                                                      const u16* __restrict__ K,
                                                      const _Float16* __restrict__ Vt,
                                                      u16* __restrict__ AO) {
    const int u  = blockIdx.x;
    const int qt = (u < 256) ? (15 - (u >> 5)) : ((u >> 5) - 8);
    const int bh = u & 31;
    const int b  = bh >> 4, h = bh & 15;
    const int q0 = qt * 128;
    const int tid = threadIdx.x, w = tid >> 6, lane = tid & 63;
    const int lm = lane & 15, quad = lane >> 4;

    __shared__ __align__(16) u16      lsK[2][128 * 64];   // [key][dim], col-swizzled
    __shared__ __align__(16) _Float16 lsV[2][64 * 128];   // [dim][key], 16B-block swizzled

    bf16x8 qb[2][2];              // [qi][ks]; wave w owns q-rows w*32 .. w*32+31
#pragma unroll
    for (int qi = 0; qi < 2; ++qi)
#pragma unroll
        for (int ks = 0; ks < 2; ++ks)
            qb[qi][ks] = *(const bf16x8*)
                &Q[(size_t)(b * SEQ + q0 + w * 32 + qi * 16 + lm) * DM + h * DH + ks * 32 + quad * 8];

    const floatx4 z4 = {0.f, 0.f, 0.f, 0.f};
    floatx4 o[2][4];              // O^T[d][q]: d = dt*16+quad*4+r, q = qi-fragment lm
#pragma unroll
    for (int qi = 0; qi < 2; ++qi)
#pragma unroll
        for (int dt = 0; dt < 4; ++dt) o[qi][dt] = z4;
    float lsum[2] = {0.f, 0.f};

    auto stageKV = [&](int buf, int kt) {
#pragma unroll
        for (int rep = 0; rep < 4; ++rep) {
            int f = rep * 256 + tid;
            int krow = f >> 3, kcb = (f & 7) ^ (krow & 7);
            async16(&K[(size_t)(b * SEQ + kt * 128 + krow) * DM + h * DH + kcb * 8],
                    &lsK[buf][f * 8]);
            int d = f >> 4, gbs = (f & 15) ^ ((d >> 1) & 7);
            async16(&Vt[(size_t)(bh * DH + d) * SEQ + kt * 128 + gbs * 8],
                    &lsV[buf][f * 8]);
        }
    };

    stageKV(0, 0);
    for (int kt = 0; kt <= qt; ++kt) {
        __syncthreads();
        if (kt < qt) stageKV((kt + 1) & 1, kt + 1);
        const u16*      Lk = lsK[kt & 1];
        const _Float16* Lv = lsV[kt & 1];

        // QK^T: each ka fragment read once, feeds both q-fragments
        floatx4 s4[2][8];
#pragma unroll
        for (int qi = 0; qi < 2; ++qi)
#pragma unroll
            for (int st = 0; st < 8; ++st) s4[qi][st] = z4;
#pragma unroll
        for (int ks = 0; ks < 2; ++ks) {
            const int cbl = ((ks * 4 + quad) ^ (lm & 7)) * 8;
#pragma unroll
            for (int st = 0; st < 8; ++st) {
                bf16x8 ka = *(const bf16x8*)&Lk[(st * 16 + lm) * 64 + cbl];
#pragma unroll
                for (int qi = 0; qi < 2; ++qi)
                    s4[qi][st] = __builtin_amdgcn_mfma_f32_16x16x32_bf16(ka, qb[qi][ks], s4[qi][st], 0, 0, 0);
            }
        }

        // per-st: softmax (both qi) -> pack -> PV (va read once, feeds both qi)
        const bool diag = (kt == qt);
#pragma unroll
        for (int st = 0; st < 8; ++st) {
            halfx4 pb2[2];
#pragma unroll
            for (int qi = 0; qi < 2; ++qi) {
#pragma unroll
                for (int r = 0; r < 4; ++r) {
                    float v = s4[qi][st][r];
                    if (diag) {
                        int keyloc = st * 16 + quad * 4 + r;
                        if (keyloc > w * 32 + qi * 16 + lm) v = -1e30f;
                    }
                    v = exp2f(v);
                    lsum[qi] += v;
                    s4[qi][st][r] = v;
                }
                uintx2 pk2;
                pk2.x = __builtin_bit_cast(u32, __builtin_amdgcn_cvt_pkrtz(s4[qi][st][0], s4[qi][st][1]));
                pk2.y = __builtin_bit_cast(u32, __builtin_amdgcn_cvt_pkrtz(s4[qi][st][2], s4[qi][st][3]));
                pb2[qi] = __builtin_bit_cast(halfx4, pk2);
            }
#pragma unroll
            for (int dt = 0; dt < 4; ++dt) {
                int drow = dt * 16 + lm;
                int sbs = (st * 2 + (quad >> 1)) ^ ((drow >> 1) & 7);
                halfx4 va = *(const halfx4*)&Lv[drow * 128 + sbs * 8 + (quad & 1) * 4];
#pragma unroll
                for (int qi = 0; qi < 2; ++qi)
                    o[qi][dt] = __builtin_amdgcn_mfma_f32_16x16x16f16(va, pb2[qi], o[qi][dt], 0, 0, 0);
            }
        }
    }

    // row-sum across the 4 quads holding q = lm
    float rl[2];
#pragma unroll
    for (int qi = 0; qi < 2; ++qi) {
        lsum[qi] += __shfl_xor(lsum[qi], 16);
        lsum[qi] += __shfl_xor(lsum[qi], 32);
        rl[qi] = 1.0f / lsum[qi];
    }

    // epilogue: O^T (reg) -> LDS (swizzled natural [q][d]) -> shuffled-frag AO store
    __syncthreads();                       // all waves done with lsK/lsV
    u16* eb = (u16*)&lsK[0][0];            // 128x64 bf16 = 16 KB
#pragma unroll
    for (int qi = 0; qi < 2; ++qi) {
        const int q = w * 32 + qi * 16 + lm;
#pragma unroll
        for (int dt = 0; dt < 4; ++dt) {
            uint2 pk;
            pk.x = (u32)f2bf(o[qi][dt][0] * rl[qi]) | ((u32)f2bf(o[qi][dt][1] * rl[qi]) << 16);
            pk.y = (u32)f2bf(o[qi][dt][2] * rl[qi]) | ((u32)f2bf(o[qi][dt][3] * rl[qi]) << 16);
            int ch = (dt * 2 + (quad >> 1)) ^ (lm & 7);
            *(uint2*)&eb[q * 64 + ch * 8 + (quad & 1) * 4] = pk;
        }
    }
    __syncthreads();
    const size_t rowblk0 = (size_t)((b * SEQ + q0) >> 4);
#pragma unroll
    for (int rbi = 0; rbi < 2; ++rbi) {
#pragma unroll
        for (int kt = 0; kt < 2; ++kt) {
            uint4 v = *(const uint4*)&eb[((w * 2 + rbi) * 16 + lm) * 64 + ((kt * 4 + quad) ^ (lm & 7)) * 8];
            *(uint4*)&AO[((rowblk0 + w * 2 + rbi) * 32 + (h * 2 + kt)) * 512 + lane * 8] = v;
        }
    }
}

extern "C" void kernel_launch(void* const* d_in, const int* in_sizes, int n_in,
                              void* d_out, int out_size, void* d_ws, size_t ws_size,
                              hipStream_t stream) {
    const float* x   = (const float*)d_in[0];
    const int*   pos = (const int*)d_in[1];
    float* out = (float*)d_out;

    u16* ws = (u16*)d_ws;
    const size_t MD = (size_t)MM * DM;
    const size_t DD = (size_t)DM * DM;
    u16* Xsh = ws;                        // shuffled X; dead after QKV -> reused as AOsh
    u16* Wsh = ws + MD;                   // 4 shuffled weights (q,k,v,o)
    u16* Qbf = ws + MD + 4 * DD;          // natural layouts
    u16* Kbf = Qbf + MD;
    u16* VtB = Kbf + MD;                  // f16 V^T (written by QKV z==2 epilogue)
    float2* ropetab = (float2*)(VtB + MD);
    _Float16* Vt = (_Float16*)VtB;
    u16* AOsh = Xsh;

    // prep: bf16 shuffled X + 4 W, RoPE table (one launch)
    prep_kernel<<<dim3(128, 16), 256, 0, stream>>>(
        x, (const float*)d_in[2], (const float*)d_in[3], (const float*)d_in[4],
        (const float*)d_in[5], Xsh, Wsh, pos, ropetab);

    // fused Q/K/V projections (z-fused: A staged once, 3x MFMA per staged byte);
    // RoPE fused on Q,K; softmax scale folded into Q; V^T f16 written directly
    gemm_f<3, false><<<dim3(64, 8), 256, 0, stream>>>(
        Xsh, Wsh, Qbf, nullptr, Vt, ropetab);

    // causal flash attention (writes AO in shuffled-frag layout)
    attn_kernel<<<dim3(512), 256, 0, stream>>>(Qbf, Kbf, Vt, AOsh);

    // output projection -> fp32 d_out
    gemm_f<1, true><<<dim3(64, 8), 256, 0, stream>>>(
        AOsh, Wsh + 3 * DD, nullptr, out, nullptr, ropetab);
}